// Round 3
// baseline (9193.935 us; speedup 1.0000x reference)
//
#include <hip/hip_runtime.h>

#define NN 10000
#define EE 160000
#define CC 32
#define NBAS 128
#define HH 64
#define LL 3

__device__ __forceinline__ float sigmoidf_(float x) { return 1.0f / (1.0f + expf(-x)); }

// ---------------------------------------------------------------------------
// geometry helpers (shared by k_edge_pre and k_out_edge)
__device__ __forceinline__ void edge_geom(const float* pos, int src, int dst,
                                          float& inv_r, float& u, float& pref,
                                          float& x, float& y, float& z) {
    float vx = pos[dst * 3 + 0] - pos[src * 3 + 0];
    float vy = pos[dst * 3 + 1] - pos[src * 3 + 1];
    float vz = pos[dst * 3 + 2] - pos[src * 3 + 2];
    float r2 = vx * vx + vy * vy + vz * vz + 1e-12f;
    float r = sqrtf(r2);
    inv_r = 1.0f / r;
    u = fminf(r * 0.2f, 1.0f);   // r/RC, RC=5
    const float PI = 3.14159265358979f;
    float env = 0.5f * (cosf(PI * u) + 1.0f);
    pref = env * 0.6324555320336759f * inv_r;  // sqrt(2/RC)
    x = vx * inv_r; y = vy * inv_r; z = vz * inv_r;
}

__device__ __forceinline__ void sph_all(float x, float y, float z, float* shv) {
    const float s3 = 1.7320508075688772f, s5 = 2.23606797749979f, s15 = 3.872983346207417f;
    const float c1 = 2.0916500663351885f;  // sqrt(35/8)
    const float c2 = 10.246950765959598f;  // sqrt(105)
    const float c3 = 1.6201851746019649f;  // sqrt(21/8)
    const float c4 = 1.3228756555322954f;  // sqrt(7)/2
    const float c5 = 5.123475382979799f;   // sqrt(105)/2
    shv[0] = 1.0f;
    shv[1] = s3 * x; shv[2] = s3 * y; shv[3] = s3 * z;
    shv[4] = s15 * x * y;
    shv[5] = s15 * y * z;
    shv[6] = 0.5f * s5 * (3.0f * z * z - 1.0f);
    shv[7] = s15 * x * z;
    shv[8] = 0.5f * s15 * (x * x - y * y);
    shv[9]  = c1 * y * (3.0f * x * x - y * y);
    shv[10] = c2 * x * y * z;
    shv[11] = c3 * y * (5.0f * z * z - 1.0f);
    shv[12] = c4 * (5.0f * z * z * z - 3.0f * z);
    shv[13] = c3 * x * (5.0f * z * z - 1.0f);
    shv[14] = c5 * z * (x * x - y * y);
    shv[15] = c1 * x * (x * x - 3.0f * y * y);
}

// ---------------------------------------------------------------------------
// f[n][c][slot] layout (N, C, 16), slot = l*l + m (l=0..3)
__global__ void k_init_f(const float* __restrict__ ne, const int* __restrict__ species,
                         float* __restrict__ f) {
    int idx = blockIdx.x * blockDim.x + threadIdx.x;
    if (idx >= NN * CC * 16) return;
    int m = idx & 15;
    int c = (idx >> 4) & 31;
    int n = idx >> 9;
    f[idx] = (m == 0) ? ne[species[n] * CC + c] : 0.0f;
}

// ---------------------------------------------------------------------------
// K1: per-edge radial basis + MLP layer 1 + spherical harmonics (stored)
__global__ __launch_bounds__(256) void k_edge_pre(
    const float* __restrict__ pos, const float* __restrict__ rw1, const float* __restrict__ rb1,
    const int* __restrict__ ei, float* __restrict__ hbuf, float* __restrict__ shbuf) {
    __shared__ float rb_s[4][NBAS];
    int w = threadIdx.x >> 6, lane = threadIdx.x & 63;
    int e = blockIdx.x * 4 + w;
    int src = ei[e], dst = ei[EE + e];
    float inv_r, u, pref, x, y, z;
    edge_geom(pos, src, dst, inv_r, u, pref, x, y, z);
    const float PI = 3.14159265358979f;
#pragma unroll
    for (int rep = 0; rep < 2; rep++) {
        int k = lane + rep * 64;
        rb_s[w][k] = pref * sinf(PI * (float)(k + 1) * u);
    }
    float shv[16];
    sph_all(x, y, z, shv);
    if (lane < 16) {
        float v = shv[0];
#pragma unroll
        for (int k = 1; k < 16; k++) v = (lane == k) ? shv[k] : v;
        shbuf[e * 16 + lane] = v;
    }
    __syncthreads();
    float acc = rb1[lane];
#pragma unroll 8
    for (int n = 0; n < NBAS; n++) acc += rb_s[w][n] * rw1[n * HH + lane];
    acc = acc * sigmoidf_(acc);
    hbuf[e * HH + lane] = acc;
}

// ---------------------------------------------------------------------------
// K2: per-layer edge messages, scatter into agg[dst] via atomics
__global__ __launch_bounds__(256) void k_edge_msg(
    const float* __restrict__ hbuf, const float* __restrict__ shbuf,
    const float* __restrict__ rw2, const float* __restrict__ rb2,
    const float* __restrict__ f_cur, const int* __restrict__ ei,
    float* __restrict__ agg, int t) {
    __shared__ float h_s[4][HH];
    __shared__ float s_s[4][CC];
    __shared__ float sh_s[4][16];
    int w = threadIdx.x >> 6, lane = threadIdx.x & 63;
    int e = blockIdx.x * 4 + w;
    int src = ei[e], dst = ei[EE + e];
    h_s[w][lane] = hbuf[e * HH + lane];
    if (lane < CC) s_s[w][lane] = f_cur[(src * CC + lane) * 16];
    if (lane < 16) sh_s[w][lane] = shbuf[e * 16 + lane];
    __syncthreads();
#pragma unroll
    for (int rep = 0; rep < 2; rep++) {
        int o = lane + rep * 64;  // o = l*32 + c
        int l = o >> 5, c = o & 31;
        int col = t * 128 + o;    // column in rw2 (H, 384)
        float acc = rb2[col];
#pragma unroll 8
        for (int j = 0; j < HH; j++) acc += h_s[w][j] * rw2[j * 384 + col];
        float a = acc * s_s[w][c];
        int dl = 2 * l + 1, mo = l * l;
        float* dstp = agg + ((size_t)dst * CC + c) * 16 + mo;
        for (int m = 0; m < dl; m++) atomicAdd(dstp + m, a * sh_s[w][mo + m]);
    }
}

// ---------------------------------------------------------------------------
// K3: per-layer node update
__global__ __launch_bounds__(256) void k_node(
    const float* __restrict__ f_cur, const float* __restrict__ agg,
    const float* __restrict__ self_w, const float* __restrict__ msg_w,
    const float* __restrict__ gate_w, float* __restrict__ f_next, int t) {
    __shared__ float new_s[4][CC * 16];
    __shared__ float gate_s[4][CC];
    int w = threadIdx.x >> 6, lane = threadIdx.x & 63;
    int n = blockIdx.x * 4 + w;
    int d = lane & 31, mg = lane >> 5;
#pragma unroll
    for (int k = 0; k < 8; k++) {
        int m = mg + 2 * k;
        int l = (m == 0) ? 0 : (m < 4) ? 1 : (m < 9) ? 2 : 3;
        const float* sw = self_w + (size_t)((t * 4 + l) * CC) * CC + d;
        const float* mw = msg_w + (size_t)((t * 4 + l) * CC) * CC + d;
        const float* fp = f_cur + (size_t)n * CC * 16 + m;
        const float* ap = agg + (size_t)n * CC * 16 + m;
        float acc = 0.0f;
#pragma unroll 8
        for (int c = 0; c < CC; c++)
            acc += fp[c * 16] * sw[c * CC] + ap[c * 16] * mw[c * CC];
        new_s[w][d * 16 + m] = acc;
    }
    __syncthreads();
    if (mg == 0) {
        float g = 0.0f;
#pragma unroll 8
        for (int c = 0; c < CC; c++) g += new_s[w][c * 16 + 0] * gate_w[((size_t)t * CC + c) * CC + d];
        gate_s[w][d] = sigmoidf_(g);
    }
    __syncthreads();
#pragma unroll
    for (int k = 0; k < 8; k++) {
        int m = mg + 2 * k;
        float v = new_s[w][d * 16 + m];
        if (m == 0) v = v * sigmoidf_(v);
        else v *= gate_s[w][d];
        f_next[((size_t)n * CC + d) * 16 + m] = v;
    }
}

// ---------------------------------------------------------------------------
// K4a: node output relayout (node region of out only)
__global__ void k_out_node(const float* __restrict__ f, float* __restrict__ out) {
    int idx = blockIdx.x * blockDim.x + threadIdx.x;
    if (idx >= NN * 512) return;
    int n = idx >> 9, q = idx & 511;
    int l, c, m;
    if (q < 32) { l = 0; c = q; m = 0; }
    else if (q < 128) { l = 1; c = (q - 32) / 3; m = (q - 32) % 3; }
    else if (q < 288) { l = 2; c = (q - 128) / 5; m = (q - 128) % 5; }
    else { l = 3; c = (q - 288) / 7; m = (q - 288) % 7; }
    out[idx] = f[((size_t)n * CC + c) * 16 + l * l + m];
}

// copy slot-0 of final f to small ws buffer (so k_out_edge is scratch-free)
__global__ void k_copy_f0(const float* __restrict__ f, float* __restrict__ f0) {
    int idx = blockIdx.x * blockDim.x + threadIdx.x;
    if (idx >= NN * CC) return;
    f0[idx] = f[(size_t)idx * 16];
}

// ---------------------------------------------------------------------------
// K4b: edge output — RECOMPUTES h and sh from pos (no main-scratch dependence)
__global__ __launch_bounds__(256) void k_out_edge(
    const float* __restrict__ pos, const float* __restrict__ rw1, const float* __restrict__ rb1,
    const float* __restrict__ edge_w, const float* __restrict__ edge_b,
    const float* __restrict__ f0, const int* __restrict__ ei, float* __restrict__ out) {
    __shared__ float rb_s[4][NBAS];
    __shared__ float h_s[4][HH];
    __shared__ float g_s[4][CC];
    __shared__ float sh_s[4][16];
    int w = threadIdx.x >> 6, lane = threadIdx.x & 63;
    int e = blockIdx.x * 4 + w;
    int src = ei[e], dst = ei[EE + e];
    float inv_r, u, pref, x, y, z;
    edge_geom(pos, src, dst, inv_r, u, pref, x, y, z);
    const float PI = 3.14159265358979f;
#pragma unroll
    for (int rep = 0; rep < 2; rep++) {
        int k = lane + rep * 64;
        rb_s[w][k] = pref * sinf(PI * (float)(k + 1) * u);
    }
    float shv[16];
    sph_all(x, y, z, shv);
    if (lane < 16) {
        float v = shv[0];
#pragma unroll
        for (int k = 1; k < 16; k++) v = (lane == k) ? shv[k] : v;
        sh_s[w][lane] = v;
    }
    if (lane < CC) g_s[w][lane] = f0[src * CC + lane] + f0[dst * CC + lane];
    __syncthreads();
    float acc = rb1[lane];
#pragma unroll 8
    for (int n = 0; n < NBAS; n++) acc += rb_s[w][n] * rw1[n * HH + lane];
    h_s[w][lane] = acc * sigmoidf_(acc);
    __syncthreads();
    size_t orow = ((size_t)NN + e) * 512;
#pragma unroll
    for (int rep = 0; rep < 2; rep++) {
        int o = lane + rep * 64;  // l*32+c
        int l = o >> 5, c = o & 31;
        float a = edge_b[o];
#pragma unroll 8
        for (int j = 0; j < HH; j++) a += h_s[w][j] * edge_w[j * 128 + o];
        float base = a * g_s[w][c];
        int dl = 2 * l + 1, mo = l * l, co = 32 * l * l;
        for (int m = 0; m < dl; m++) out[orow + co + c * dl + m] = base * sh_s[w][mo + m];
    }
}

// ---------------------------------------------------------------------------
extern "C" void kernel_launch(void* const* d_in, const int* in_sizes, int n_in,
                              void* d_out, int out_size, void* d_ws, size_t ws_size,
                              hipStream_t stream) {
    const float* pos        = (const float*)d_in[0];
    const float* node_embed = (const float*)d_in[1];
    const float* rw1        = (const float*)d_in[2];
    const float* rb1        = (const float*)d_in[3];
    const float* rw2        = (const float*)d_in[4];
    const float* rb2        = (const float*)d_in[5];
    const float* self_w     = (const float*)d_in[6];
    const float* msg_w      = (const float*)d_in[7];
    const float* gate_w     = (const float*)d_in[8];
    const float* edge_w     = (const float*)d_in[9];
    const float* edge_b     = (const float*)d_in[10];
    const int* species      = (const int*)d_in[11];
    const int* ei           = (const int*)d_in[12];
    float* out = (float*)d_out;

    // --- scratch placement (ws-size robust) ---
    float* f0buf = (float*)d_ws;                                 // N*32 floats
    const size_t F0_BYTES = (size_t)NN * CC * 4;                 // 1,280,000
    const size_t MAIN_FLOATS = (size_t)EE * HH + (size_t)EE * 16
                             + 3 * (size_t)NN * 512;             // 28,160,000
    float* scratch;
    if (ws_size >= F0_BYTES + MAIN_FLOATS * 4) {
        scratch = (float*)((char*)d_ws + F0_BYTES);
    } else {
        // edge-row region of out (f32): 327.68 MB, only written by final kernel
        scratch = out + (size_t)NN * 512;
    }
    float* hbuf  = scratch;                     // E*64
    float* shbuf = hbuf + (size_t)EE * HH;      // E*16
    float* fA    = shbuf + (size_t)EE * 16;     // N*512
    float* fB    = fA + (size_t)NN * 512;       // N*512
    float* agg   = fB + (size_t)NN * 512;       // N*512

    k_init_f<<<(NN * CC * 16 + 255) / 256, 256, 0, stream>>>(node_embed, species, fA);
    k_edge_pre<<<EE / 4, 256, 0, stream>>>(pos, rw1, rb1, ei, hbuf, shbuf);

    float* fc = fA;
    float* fn = fB;
    for (int t = 0; t < LL; t++) {
        hipMemsetAsync(agg, 0, (size_t)NN * 512 * sizeof(float), stream);
        k_edge_msg<<<EE / 4, 256, 0, stream>>>(hbuf, shbuf, rw2, rb2, fc, ei, agg, t);
        k_node<<<NN / 4, 256, 0, stream>>>(fc, agg, self_w, msg_w, gate_w, fn, t);
        float* tmp = fc; fc = fn; fn = tmp;
    }

    k_out_node<<<(NN * 512 + 255) / 256, 256, 0, stream>>>(fc, out);
    k_copy_f0<<<(NN * CC + 255) / 256, 256, 0, stream>>>(fc, f0buf);
    k_out_edge<<<EE / 4, 256, 0, stream>>>(pos, rw1, rb1, edge_w, edge_b, f0buf, ei, out);
}

// Round 4
// 1974.341 us; speedup vs baseline: 4.6567x; 4.6567x over previous
//
#include <hip/hip_runtime.h>

#define NN 10000
#define EE 160000
#define CC 32
#define NBAS 128
#define HH 64
#define LL 3

__device__ __forceinline__ float sigmoidf_(float x) { return 1.0f / (1.0f + expf(-x)); }

// ---------------------------------------------------------------------------
__device__ __forceinline__ void edge_geom(const float* pos, int src, int dst,
                                          float& inv_r, float& u, float& pref,
                                          float& x, float& y, float& z) {
    float vx = pos[dst * 3 + 0] - pos[src * 3 + 0];
    float vy = pos[dst * 3 + 1] - pos[src * 3 + 1];
    float vz = pos[dst * 3 + 2] - pos[src * 3 + 2];
    float r2 = vx * vx + vy * vy + vz * vz + 1e-12f;
    float r = sqrtf(r2);
    inv_r = 1.0f / r;
    u = fminf(r * 0.2f, 1.0f);   // r/RC, RC=5
    const float PI = 3.14159265358979f;
    float env = 0.5f * (cosf(PI * u) + 1.0f);
    pref = env * 0.6324555320336759f * inv_r;  // sqrt(2/RC)
    x = vx * inv_r; y = vy * inv_r; z = vz * inv_r;
}

__device__ __forceinline__ void sph_all(float x, float y, float z, float* shv) {
    const float s3 = 1.7320508075688772f, s5 = 2.23606797749979f, s15 = 3.872983346207417f;
    const float c1 = 2.0916500663351885f;
    const float c2 = 10.246950765959598f;
    const float c3 = 1.6201851746019649f;
    const float c4 = 1.3228756555322954f;
    const float c5 = 5.123475382979799f;
    shv[0] = 1.0f;
    shv[1] = s3 * x; shv[2] = s3 * y; shv[3] = s3 * z;
    shv[4] = s15 * x * y;
    shv[5] = s15 * y * z;
    shv[6] = 0.5f * s5 * (3.0f * z * z - 1.0f);
    shv[7] = s15 * x * z;
    shv[8] = 0.5f * s15 * (x * x - y * y);
    shv[9]  = c1 * y * (3.0f * x * x - y * y);
    shv[10] = c2 * x * y * z;
    shv[11] = c3 * y * (5.0f * z * z - 1.0f);
    shv[12] = c4 * (5.0f * z * z * z - 3.0f * z);
    shv[13] = c3 * x * (5.0f * z * z - 1.0f);
    shv[14] = c5 * z * (x * x - y * y);
    shv[15] = c1 * x * (x * x - 3.0f * y * y);
}

// ---------------------------------------------------------------------------
// CSR build: degree histogram, single-block scan, scatter
__global__ void k_deg(const int* __restrict__ ei, int* __restrict__ deg) {
    int e = blockIdx.x * blockDim.x + threadIdx.x;
    if (e < EE) atomicAdd(&deg[ei[EE + e]], 1);
}

__global__ __launch_bounds__(256) void k_scan(const int* __restrict__ deg, int* __restrict__ rowptr) {
    __shared__ int part[256];
    const int CHUNK = 40;  // 256*40 = 10240 >= NN
    int tid = threadIdx.x;
    int s = 0;
#pragma unroll
    for (int k = 0; k < CHUNK; k++) {
        int idx = tid * CHUNK + k;
        if (idx < NN) s += deg[idx];
    }
    part[tid] = s;
    __syncthreads();
    for (int off = 1; off < 256; off <<= 1) {
        int v = (tid >= off) ? part[tid - off] : 0;
        __syncthreads();
        part[tid] += v;
        __syncthreads();
    }
    int run = (tid > 0) ? part[tid - 1] : 0;
#pragma unroll
    for (int k = 0; k < CHUNK; k++) {
        int idx = tid * CHUNK + k;
        if (idx < NN) { rowptr[idx] = run; run += deg[idx]; }
    }
    if (tid == 255) rowptr[NN] = run;  // == EE
}

__global__ void k_scatter(const int* __restrict__ ei, const int* __restrict__ rowptr,
                          int* __restrict__ cursor, int* __restrict__ csr) {
    int e = blockIdx.x * blockDim.x + threadIdx.x;
    if (e >= EE) return;
    int d = ei[EE + e];
    int slot = atomicAdd(&cursor[d], 1);
    csr[rowptr[d] + slot] = e;
}

// ---------------------------------------------------------------------------
// f[n][c][slot] layout (N, C, 16), slot = l*l + m; also compact f0 (N,C)
__global__ void k_init_f(const float* __restrict__ ne, const int* __restrict__ species,
                         float* __restrict__ f, float* __restrict__ f0) {
    int idx = blockIdx.x * blockDim.x + threadIdx.x;
    if (idx >= NN * CC * 16) return;
    int m = idx & 15;
    int c = (idx >> 4) & 31;
    int n = idx >> 9;
    float v = (m == 0) ? ne[species[n] * CC + c] : 0.0f;
    f[idx] = v;
    if (m == 0) f0[n * CC + c] = v;
}

// ---------------------------------------------------------------------------
// K1: per-edge radial basis + MLP layer 1 + spherical harmonics (stored)
__global__ __launch_bounds__(256) void k_edge_pre(
    const float* __restrict__ pos, const float* __restrict__ rw1, const float* __restrict__ rb1,
    const int* __restrict__ ei, float* __restrict__ hbuf, float* __restrict__ shbuf) {
    __shared__ float rw1_s[NBAS * HH];   // 32 KB
    __shared__ float rb_s[4][NBAS];
    int tid = threadIdx.x;
    for (int i = tid; i < NBAS * HH; i += 256) rw1_s[i] = rw1[i];
    int w = tid >> 6, lane = tid & 63;
    int e = blockIdx.x * 4 + w;
    int src = ei[e], dst = ei[EE + e];
    float inv_r, u, pref, x, y, z;
    edge_geom(pos, src, dst, inv_r, u, pref, x, y, z);
    const float PI = 3.14159265358979f;
#pragma unroll
    for (int rep = 0; rep < 2; rep++) {
        int k = lane + rep * 64;
        rb_s[w][k] = pref * sinf(PI * (float)(k + 1) * u);
    }
    float shv[16];
    sph_all(x, y, z, shv);
    if (lane < 16) {
        float v = shv[0];
#pragma unroll
        for (int k = 1; k < 16; k++) v = (lane == k) ? shv[k] : v;
        shbuf[e * 16 + lane] = v;
    }
    __syncthreads();
    float acc = rb1[lane];
#pragma unroll 8
    for (int n = 0; n < NBAS; n++) acc += rb_s[w][n] * rw1_s[n * HH + lane];
    acc = acc * sigmoidf_(acc);
    hbuf[e * HH + lane] = acc;
}

// ---------------------------------------------------------------------------
// K2 (new): CSR gather aggregation — one wave per node, no f32 atomics.
// Recomputes w = h@rw2[:,t*128:(t+1)*128]+rb2 per edge from hbuf.
__global__ __launch_bounds__(256) void k_agg(
    const float* __restrict__ hbuf, const float* __restrict__ shbuf,
    const float* __restrict__ rw2, const float* __restrict__ rb2,
    const float* __restrict__ f0, const int* __restrict__ ei,
    const int* __restrict__ rowptr, const int* __restrict__ csr,
    float* __restrict__ agg, int t) {
    __shared__ float rw2_s[HH * 128];    // 32 KB, layer-t panel: [j][o]
    int tid = threadIdx.x;
    for (int i = tid; i < HH * 128; i += 256) {
        int j = i >> 7, o = i & 127;
        rw2_s[i] = rw2[j * 384 + t * 128 + o];
    }
    __syncthreads();
    int w = tid >> 6, lane = tid & 63;
    int n = blockIdx.x * 4 + w;
    int c = lane & 31;
    int l0 = lane >> 5;            // 0 or 1
    int dl0 = 2 * l0 + 1, mo0 = l0 * l0;
    int l1 = 2 + (lane >> 5);      // 2 or 3
    int dl1 = 2 * l1 + 1, mo1 = l1 * l1;
    float b0 = rb2[t * 128 + lane];
    float b1 = rb2[t * 128 + 64 + lane];
    float acc0[3] = {0.f, 0.f, 0.f};
    float acc1[7] = {0.f, 0.f, 0.f, 0.f, 0.f, 0.f, 0.f};
    int beg = rowptr[n], end = rowptr[n + 1];
    for (int k = beg; k < end; k++) {
        int e = csr[k];
        int src = ei[e];
        float hval = hbuf[(size_t)e * HH + lane];                    // 256B coalesced
        float shval = (lane < 16) ? shbuf[e * 16 + lane] : 0.0f;
        float sval = f0[src * CC + c];
        float w0 = b0, w1 = b1;
#pragma unroll 8
        for (int j = 0; j < HH; j++) {
            float hj = __shfl(hval, j);
            w0 += hj * rw2_s[j * 128 + lane];
            w1 += hj * rw2_s[j * 128 + 64 + lane];
        }
        float a0 = w0 * sval;
        float a1 = w1 * sval;
#pragma unroll
        for (int m = 0; m < 3; m++)
            if (m < dl0) acc0[m] += a0 * __shfl(shval, mo0 + m);
#pragma unroll
        for (int m = 0; m < 7; m++)
            if (m < dl1) acc1[m] += a1 * __shfl(shval, mo1 + m);
    }
    float* ap = agg + ((size_t)n * CC + c) * 16;
#pragma unroll
    for (int m = 0; m < 3; m++)
        if (m < dl0) ap[mo0 + m] = acc0[m];
#pragma unroll
    for (int m = 0; m < 7; m++)
        if (m < dl1) ap[mo1 + m] = acc1[m];
}

// ---------------------------------------------------------------------------
// K3: per-layer node update (+ compact f0 output for next layer / epilogue)
__global__ __launch_bounds__(256) void k_node(
    const float* __restrict__ f_cur, const float* __restrict__ agg,
    const float* __restrict__ self_w, const float* __restrict__ msg_w,
    const float* __restrict__ gate_w, float* __restrict__ f_next,
    float* __restrict__ f0_out, int t) {
    __shared__ float new_s[4][CC * 16];
    __shared__ float gate_s[4][CC];
    int w = threadIdx.x >> 6, lane = threadIdx.x & 63;
    int n = blockIdx.x * 4 + w;
    int d = lane & 31, mg = lane >> 5;
#pragma unroll
    for (int k = 0; k < 8; k++) {
        int m = mg + 2 * k;
        int l = (m == 0) ? 0 : (m < 4) ? 1 : (m < 9) ? 2 : 3;
        const float* sw = self_w + (size_t)((t * 4 + l) * CC) * CC + d;
        const float* mw = msg_w + (size_t)((t * 4 + l) * CC) * CC + d;
        const float* fp = f_cur + (size_t)n * CC * 16 + m;
        const float* ap = agg + (size_t)n * CC * 16 + m;
        float acc = 0.0f;
#pragma unroll 8
        for (int c = 0; c < CC; c++)
            acc += fp[c * 16] * sw[c * CC] + ap[c * 16] * mw[c * CC];
        new_s[w][d * 16 + m] = acc;
    }
    __syncthreads();
    if (mg == 0) {
        float g = 0.0f;
#pragma unroll 8
        for (int c = 0; c < CC; c++) g += new_s[w][c * 16 + 0] * gate_w[((size_t)t * CC + c) * CC + d];
        gate_s[w][d] = sigmoidf_(g);
    }
    __syncthreads();
#pragma unroll
    for (int k = 0; k < 8; k++) {
        int m = mg + 2 * k;
        float v = new_s[w][d * 16 + m];
        if (m == 0) v = v * sigmoidf_(v);
        else v *= gate_s[w][d];
        f_next[((size_t)n * CC + d) * 16 + m] = v;
        if (m == 0) f0_out[n * CC + d] = v;
    }
}

// ---------------------------------------------------------------------------
// K4a: node output relayout
__global__ void k_out_node(const float* __restrict__ f, float* __restrict__ out) {
    int idx = blockIdx.x * blockDim.x + threadIdx.x;
    if (idx >= NN * 512) return;
    int n = idx >> 9, q = idx & 511;
    int l, c, m;
    if (q < 32) { l = 0; c = q; m = 0; }
    else if (q < 128) { l = 1; c = (q - 32) / 3; m = (q - 32) % 3; }
    else if (q < 288) { l = 2; c = (q - 128) / 5; m = (q - 128) % 5; }
    else { l = 3; c = (q - 288) / 7; m = (q - 288) % 7; }
    out[idx] = f[((size_t)n * CC + c) * 16 + l * l + m];
}

// ---------------------------------------------------------------------------
// K4b: edge output — recomputes h and sh from pos; reads final f0 from safe ws
__global__ __launch_bounds__(256) void k_out_edge(
    const float* __restrict__ pos, const float* __restrict__ rw1, const float* __restrict__ rb1,
    const float* __restrict__ edge_w, const float* __restrict__ edge_b,
    const float* __restrict__ f0, const int* __restrict__ ei, float* __restrict__ out) {
    __shared__ float rw1_s[NBAS * HH];   // 32 KB
    __shared__ float ew_s[HH * 128];     // 32 KB
    __shared__ float rb_s[4][NBAS];
    __shared__ float h_s[4][HH];
    __shared__ float g_s[4][CC];
    __shared__ float sh_s[4][16];
    int tid = threadIdx.x;
    for (int i = tid; i < NBAS * HH; i += 256) rw1_s[i] = rw1[i];
    for (int i = tid; i < HH * 128; i += 256) ew_s[i] = edge_w[i];
    int w = tid >> 6, lane = tid & 63;
    int e = blockIdx.x * 4 + w;
    int src = ei[e], dst = ei[EE + e];
    float inv_r, u, pref, x, y, z;
    edge_geom(pos, src, dst, inv_r, u, pref, x, y, z);
    const float PI = 3.14159265358979f;
#pragma unroll
    for (int rep = 0; rep < 2; rep++) {
        int k = lane + rep * 64;
        rb_s[w][k] = pref * sinf(PI * (float)(k + 1) * u);
    }
    float shv[16];
    sph_all(x, y, z, shv);
    if (lane < 16) {
        float v = shv[0];
#pragma unroll
        for (int k = 1; k < 16; k++) v = (lane == k) ? shv[k] : v;
        sh_s[w][lane] = v;
    }
    if (lane < CC) g_s[w][lane] = f0[src * CC + lane] + f0[dst * CC + lane];
    __syncthreads();
    float acc = rb1[lane];
#pragma unroll 8
    for (int n = 0; n < NBAS; n++) acc += rb_s[w][n] * rw1_s[n * HH + lane];
    h_s[w][lane] = acc * sigmoidf_(acc);
    __syncthreads();
    size_t orow = ((size_t)NN + e) * 512;
#pragma unroll
    for (int rep = 0; rep < 2; rep++) {
        int o = lane + rep * 64;  // l*32+c
        int l = o >> 5, c = o & 31;
        float a = edge_b[o];
#pragma unroll 8
        for (int j = 0; j < HH; j++) a += h_s[w][j] * ew_s[j * 128 + o];
        float base = a * g_s[w][c];
        int dl = 2 * l + 1, mo = l * l, co = 32 * l * l;
        for (int m = 0; m < dl; m++) out[orow + co + c * dl + m] = base * sh_s[w][mo + m];
    }
}

// ---------------------------------------------------------------------------
extern "C" void kernel_launch(void* const* d_in, const int* in_sizes, int n_in,
                              void* d_out, int out_size, void* d_ws, size_t ws_size,
                              hipStream_t stream) {
    const float* pos        = (const float*)d_in[0];
    const float* node_embed = (const float*)d_in[1];
    const float* rw1        = (const float*)d_in[2];
    const float* rb1        = (const float*)d_in[3];
    const float* rw2        = (const float*)d_in[4];
    const float* rb2        = (const float*)d_in[5];
    const float* self_w     = (const float*)d_in[6];
    const float* msg_w      = (const float*)d_in[7];
    const float* gate_w     = (const float*)d_in[8];
    const float* edge_w     = (const float*)d_in[9];
    const float* edge_b     = (const float*)d_in[10];
    const int* species      = (const int*)d_in[11];
    const int* ei           = (const int*)d_in[12];
    float* out = (float*)d_out;

    // --- scratch placement ---
    // safe ws area (always in d_ws): final-f0 copy, N*32 floats = 1.28 MB
    float* f0fin = (float*)d_ws;
    const size_t F0_BYTES = (size_t)NN * CC * 4;
    const size_t MAIN_FLOATS = (size_t)EE * HH + (size_t)EE * 16
                             + 3 * (size_t)NN * 512 + (size_t)NN * CC;
    const size_t INT_COUNT = (size_t)NN + (NN + 1) + NN + EE;
    const size_t MAIN_BYTES = MAIN_FLOATS * 4 + INT_COUNT * 4;
    float* scratch;
    if (ws_size >= F0_BYTES + MAIN_BYTES) {
        scratch = (float*)((char*)d_ws + F0_BYTES);
    } else {
        // edge-row region of out (f32): 327.68 MB, written only by k_out_edge
        scratch = out + (size_t)NN * 512;
    }
    float* hbuf   = scratch;                     // E*64
    float* shbuf  = hbuf + (size_t)EE * HH;      // E*16
    float* fA     = shbuf + (size_t)EE * 16;     // N*512
    float* fB     = fA + (size_t)NN * 512;       // N*512
    float* agg    = fB + (size_t)NN * 512;       // N*512
    float* f0ar   = agg + (size_t)NN * 512;      // N*32
    int* deg      = (int*)(f0ar + (size_t)NN * CC);
    int* rowptr   = deg + NN;                    // NN+1
    int* cursor   = rowptr + NN + 1;             // NN
    int* csr      = cursor + NN;                 // EE

    // CSR build
    hipMemsetAsync(deg, 0, (size_t)NN * 4, stream);
    hipMemsetAsync(cursor, 0, (size_t)NN * 4, stream);
    k_deg<<<(EE + 255) / 256, 256, 0, stream>>>(ei, deg);
    k_scan<<<1, 256, 0, stream>>>(deg, rowptr);
    k_scatter<<<(EE + 255) / 256, 256, 0, stream>>>(ei, rowptr, cursor, csr);

    k_init_f<<<(NN * CC * 16 + 255) / 256, 256, 0, stream>>>(node_embed, species, fA, f0ar);
    k_edge_pre<<<EE / 4, 256, 0, stream>>>(pos, rw1, rb1, ei, hbuf, shbuf);

    float* fc = fA;
    float* fn = fB;
    for (int t = 0; t < LL; t++) {
        k_agg<<<NN / 4, 256, 0, stream>>>(hbuf, shbuf, rw2, rb2, f0ar, ei, rowptr, csr, agg, t);
        float* f0o = (t == LL - 1) ? f0fin : f0ar;
        k_node<<<NN / 4, 256, 0, stream>>>(fc, agg, self_w, msg_w, gate_w, fn, f0o, t);
        float* tmp = fc; fc = fn; fn = tmp;
    }

    k_out_node<<<(NN * 512 + 255) / 256, 256, 0, stream>>>(fc, out);
    k_out_edge<<<EE / 4, 256, 0, stream>>>(pos, rw1, rb1, edge_w, edge_b, f0fin, ei, out);
}